// Round 22
// baseline (266.756 us; speedup 1.0000x reference)
//
#include <hip/hip_runtime.h>

#define OBS 128
#define HID 64
#define ACT 32
#define TT  128
#define BB  4096

typedef __attribute__((ext_vector_type(8))) short bf16x8;  // 8 bf16 (4 VGPRs)
typedef __attribute__((ext_vector_type(4))) float f32x4;

// tanh(v) = 1 - 2/(exp(2v)+1); exact at +-inf, ~1e-6 rel error (v_exp + v_rcp)
__device__ __forceinline__ float fast_tanh(float v) {
  const float e = __expf(2.0f * v);
  return 1.0f - 2.0f * __builtin_amdgcn_rcpf(e + 1.0f);
}

// f32 -> bf16 bits, round-to-nearest-even (prep + capture paths)
__device__ __forceinline__ short f2bf(float f) {
  const unsigned u = __float_as_uint(f);
  return (short)((u + 0x7FFFu + ((u >> 16) & 1u)) >> 16);
}

// HW packed f32x2 -> bf16x2 (RNE), gfx950; no builtin -> inline asm (T12/m240).
__device__ __forceinline__ unsigned cvtpk(float lo, float hi) {
  unsigned r;
  asm("v_cvt_pk_bf16_f32 %0, %1, %2" : "=v"(r) : "v"(lo), "v"(hi));
  return r;
}

// pack two f32x4 (C/D-layout quads) into one bf16x8 B-fragment (4 instrs)
__device__ __forceinline__ bf16x8 cvt8(const f32x4 s0, const f32x4 s1) {
  union { bf16x8 f; unsigned u[4]; } z;
  z.u[0] = cvtpk(s0[0], s0[1]); z.u[1] = cvtpk(s0[2], s0[3]);
  z.u[2] = cvtpk(s1[0], s1[1]); z.u[3] = cvtpk(s1[2], s1[3]);
  return z.f;
}

// pack [float4, float4] -> bf16x8
__device__ __forceinline__ bf16x8 cvt8f(const float4 lo, const float4 hi) {
  union { bf16x8 f; unsigned u[4]; } z;
  z.u[0] = cvtpk(lo.x, lo.y); z.u[1] = cvtpk(lo.z, lo.w);
  z.u[2] = cvtpk(hi.x, hi.y); z.u[3] = cvtpk(hi.z, hi.w);
  return z.f;
}

// LDS barrier: drain own ds ops, sync waves (NOT __syncthreads — no vmcnt drain)
__device__ __forceinline__ void lds_barrier() {
  asm volatile("s_waitcnt lgkmcnt(0)" ::: "memory");
  __builtin_amdgcn_s_barrier();
  asm volatile("" ::: "memory");
}

// ---------------------------------------------------------------------------
// Prep: fragment-ordered bf16 weight table in d_ws (capture uses frags 0..23;
// recur consumer gathers Wp1/Wp2 directly).
// ---------------------------------------------------------------------------
__global__ void prep_weights(const float* __restrict__ Wc1,
                             const float* __restrict__ Wc2,
                             const float* __restrict__ Wp1,
                             const float* __restrict__ Wp2,
                             short* __restrict__ ws)
{
  const int idx = blockIdx.x * blockDim.x + threadIdx.x;  // 0..(44*64-1)
  if (idx >= 44 * 64) return;
  const int f = idx >> 6, lane = idx & 63;
  const int r = lane & 15, G = lane >> 4;
  short o[8];
  if (f < 16) {
    const int m = f >> 2, kk = f & 3;  // std: k = 32kk + 8G + j
#pragma unroll
    for (int j = 0; j < 8; ++j)
      o[j] = f2bf(Wc1[(kk * 32 + 8 * G + j) * HID + 16 * m + r]);
  } else if (f < 40) {
    const int q = (f < 24) ? (f - 16) : (f < 32) ? (f - 24) : (f - 32);
    const float* W = (f < 24) ? Wc2 : (f < 32) ? Wp1 : Wp2;
    const int m = q >> 1, kk = q & 1;  // custom k-map (matches lane-resident C/D)
#pragma unroll
    for (int j = 0; j < 8; ++j) {
      const int k = (j < 4) ? (32 * kk + 4 * G + j)
                            : (32 * kk + 16 + 4 * G + (j - 4));
      o[j] = f2bf(W[k * HID + 16 * m + r]);
    }
  } else {
    const int m = f - 40;  // a-part, std map: k = HID + 8G + j
#pragma unroll
    for (int j = 0; j < 8; ++j)
      o[j] = f2bf(Wp1[(HID + 8 * G + j) * HID + 16 * m + r]);
  }
  bf16x8 v;
#pragma unroll
  for (int j = 0; j < 8; ++j) v[j] = o[j];
  *(bf16x8*)(ws + (size_t)idx * 8) = v;
}

// ---------------------------------------------------------------------------
// Phase 1: capture — BYTE-IDENTICAL to rounds 9..21 (deterministic LDS-weight
// form, HBM-bound ~65-75 us at 2 blocks/CU).
// ---------------------------------------------------------------------------
__global__ __launch_bounds__(256, 2) void capture_lds(
    const float* __restrict__ x,
    const short* __restrict__ wsw,
    const float* __restrict__ bc1, const float* __restrict__ bc2,
    float* __restrict__ capt)
{
  __shared__ bf16x8 wl[24 * 64];  // 24.5 KB fragment table

  const int tid  = threadIdx.x;
  const int lane = tid & 63;
  const int r    = lane & 15;   // tile-row (N dim)
  const int G    = lane >> 4;   // k-group
  const int wave = blockIdx.x * 4 + (tid >> 6);
  const int nwaves = gridDim.x * 4;

  for (int s = tid; s < 24 * 64; s += 256)
    wl[s] = ((const bf16x8*)wsw)[s];
  __syncthreads();

  f32x4 bias1[4], bias2[4];
#pragma unroll
  for (int m = 0; m < 4; ++m) {
    bias1[m] = *(const f32x4*)(bc1 + 16 * m + 4 * G);
    bias2[m] = *(const f32x4*)(bc2 + 16 * m + 4 * G);
  }

  for (int tile = wave; tile < (TT * BB) / 16; tile += nwaves) {
    asm volatile("" ::: "memory");

    const float* xrow = x + ((size_t)tile * 16 + r) * OBS;
    bf16x8 xa[4];
#pragma unroll
    for (int kk = 0; kk < 4; ++kk) {
      const float4 lo = *(const float4*)(xrow + kk * 32 + 8 * G);
      const float4 hi = *(const float4*)(xrow + kk * 32 + 8 * G + 4);
      bf16x8 f;
      f[0] = f2bf(lo.x); f[1] = f2bf(lo.y); f[2] = f2bf(lo.z); f[3] = f2bf(lo.w);
      f[4] = f2bf(hi.x); f[5] = f2bf(hi.y); f[6] = f2bf(hi.z); f[7] = f2bf(hi.w);
      xa[kk] = f;
    }

    float um[4][4];
#pragma unroll
    for (int m = 0; m < 4; ++m) {
      f32x4 acc = bias1[m];
#pragma unroll
      for (int kk = 0; kk < 4; ++kk)
        acc = __builtin_amdgcn_mfma_f32_16x16x32_bf16(wl[(m * 4 + kk) * 64 + lane],
                                                      xa[kk], acc, 0, 0, 0);
#pragma unroll
      for (int q = 0; q < 4; ++q) um[m][q] = fast_tanh(acc[q]);
    }

    bf16x8 b2[2];
#pragma unroll
    for (int kk = 0; kk < 2; ++kk) {
      bf16x8 f;
#pragma unroll
      for (int j = 0; j < 4; ++j) f[j]     = f2bf(um[2 * kk][j]);
#pragma unroll
      for (int j = 0; j < 4; ++j) f[4 + j] = f2bf(um[2 * kk + 1][j]);
      b2[kk] = f;
    }

    float* crow = capt + ((size_t)tile * 16 + r) * HID;
#pragma unroll
    for (int m = 0; m < 4; ++m) {
      f32x4 acc = bias2[m];
#pragma unroll
      for (int kk = 0; kk < 2; ++kk)
        acc = __builtin_amdgcn_mfma_f32_16x16x32_bf16(wl[(16 + m * 2 + kk) * 64 + lane],
                                                      b2[kk], acc, 0, 0, 0);
      float4 o;
      o.x = fast_tanh(acc[0]); o.y = fast_tanh(acc[1]);
      o.z = fast_tanh(acc[2]); o.w = fast_tanh(acc[3]);
      *(float4*)(crow + 16 * m + 4 * G) = o;
    }
  }
}

// producer: issue global loads for step t into registers (fire-and-forget)
#define P_LOAD(t)                                                           \
  do {                                                                      \
    const size_t rb = (size_t)(t) * BB + row0;                              \
    const float* zp = z1buf + rb * HID;                                     \
    _Pragma("unroll")                                                       \
    for (int i = 0; i < 4; ++i)                                             \
      zv[i] = *(const float4*)(zp + i * 256 + lane * 4);                    \
    const float* ap = a + rb * ACT;                                         \
    _Pragma("unroll")                                                       \
    for (int i = 0; i < 2; ++i)                                             \
      av[i] = *(const float4*)(ap + i * 256 + lane * 4);                    \
    gv = (lane < 16) ? g[rb + lane] : 0.0f;                                 \
  } while (0)

// producer: write the register-buffered slab (loaded LAST iteration — one
// full step of vmcnt slack) into ring slot p
#define P_WRITE(p)                                                          \
  do {                                                                      \
    _Pragma("unroll")                                                       \
    for (int i = 0; i < 4; ++i) {                                           \
      const int rr = i * 4 + (lane >> 4), cc = (lane & 15) * 4;             \
      *(float4*)&zS[p][rr][cc] = zv[i];                                     \
    }                                                                       \
    _Pragma("unroll")                                                       \
    for (int i = 0; i < 2; ++i) {                                           \
      const int rr = i * 8 + (lane >> 3), cc = (lane & 7) * 4;              \
      *(float4*)&aS[p][rr][cc] = av[i];                                     \
    }                                                                       \
    if (lane < 16) gS[p][lane] = gv;                                        \
  } while (0)

// ---------------------------------------------------------------------------
// Phase 2: recurrence — P/C, convergent barriers (r21 skeleton, passed),
// with (a) REG-PIPELINED producer: P_LOAD(t+2) issued at step t, P_WRITE uses
// registers loaded one full iteration (~2300 cyc) earlier -> L3/HBM latency
// never on the barrier path (r21's lockstep P_STAGE exposed ~500 cyc/step);
// (b) consumer = best-measured r17 body (pinned global-gathered weights,
// in-loop pins, cvt_pk). Grid: 256 blocks x 128 threads (1 block/CU).
// ---------------------------------------------------------------------------
__global__ __launch_bounds__(128, 1) void recur_pc3(
    const float* __restrict__ h0,
    const float* __restrict__ g,
    const float* __restrict__ a,
    const float* __restrict__ Wp1, const float* __restrict__ bp1,
    const float* __restrict__ Wp2, const float* __restrict__ bp2,
    const float* __restrict__ z1buf,
    float* __restrict__ outs, float* __restrict__ hlast)
{
  __shared__ float zS[2][16][68];  // z ring slot: 16 rows x 64 (+4 pad)
  __shared__ float aS[2][16][36];  // a ring slot: 16 rows x 32 (+4 pad)
  __shared__ float gS[2][16];

  const int tid  = threadIdx.x;
  const int lane = tid & 63;
  const int wid  = __builtin_amdgcn_readfirstlane(tid >> 6);
  const int row0 = blockIdx.x * 16;
  const int r    = lane & 15;
  const int G    = lane >> 4;
  const int row  = row0 + r;

  // consumer weights: gathered unconditionally (both waves; once-only cost,
  // keeps every barrier out of divergent code)
  bf16x8 w1h[4][2], w2t[4][2], w1a[4];
#pragma unroll
  for (int m = 0; m < 4; ++m) {
#pragma unroll
    for (int kk = 0; kk < 2; ++kk) {
      bf16x8 f1, f2;
#pragma unroll
      for (int j = 0; j < 8; ++j) {
        const int k = (j < 4) ? (32 * kk + 4 * G + j)
                              : (32 * kk + 16 + 4 * G + (j - 4));
        f1[j] = f2bf(Wp1[k * HID + 16 * m + r]);
        f2[j] = f2bf(Wp2[k * HID + 16 * m + r]);
      }
      w1h[m][kk] = f1;
      w2t[m][kk] = f2;
    }
    bf16x8 fa;  // a-part, std map: k = HID + 8G + j
#pragma unroll
    for (int j = 0; j < 8; ++j)
      fa[j] = f2bf(Wp1[(HID + 8 * G + j) * HID + 16 * m + r]);
    w1a[m] = fa;
  }
  f32x4 bias1[4], bias2[4];
#pragma unroll
  for (int m = 0; m < 4; ++m) {
    bias1[m] = *(const f32x4*)(bp1 + 16 * m + 4 * G);
    bias2[m] = *(const f32x4*)(bp2 + 16 * m + 4 * G);
  }
  f32x4 hm[4];
#pragma unroll
  for (int m = 0; m < 4; ++m)
    hm[m] = *(const f32x4*)(h0 + (size_t)row * HID + 16 * m + 4 * G);
  bf16x8 hb0 = cvt8(hm[0], hm[1]);
  bf16x8 hb1 = cvt8(hm[2], hm[3]);

  // producer register pipeline buffers
  float4 zv[4], av[2];
  float gv = 0.0f;

  if (wid == 1) {
    P_LOAD(0);
    P_WRITE(0);     // slot 0 = step 0 (vmcnt wait here, prologue only)
    P_LOAD(1);      // regs now hold step 1 (written next iteration)
  }
  lds_barrier();    // convergent

  for (int t = 0; t < TT; ++t) {
    if (wid == 1) {
      // ---- PRODUCER: write step t+1 (regs from last iter), prefetch t+2 ----
      P_WRITE((t + 1) & 1);
      const int tn2 = (t + 2 < TT) ? (t + 2) : (TT - 1);  // clamp
      P_LOAD(tn2);
    } else {
      // ---- CONSUMER: step t from slot t&1 (r17 body) ----
      // in-loop pin: weights/biases are loop-carried opaque values
#pragma unroll
      for (int m = 0; m < 4; ++m) {
        asm volatile("" : "+v"(w1h[m][0]), "+v"(w1h[m][1]));
        asm volatile("" : "+v"(w2t[m][0]), "+v"(w2t[m][1]));
        asm volatile("" : "+v"(w1a[m]));
        asm volatile("" : "+v"(bias1[m]), "+v"(bias2[m]));
      }

      const int p = t & 1;
      const f32x4 Z0 = *(const f32x4*)&zS[p][r][4 * G];
      const f32x4 Z1 = *(const f32x4*)&zS[p][r][16 + 4 * G];
      const f32x4 Z2 = *(const f32x4*)&zS[p][r][32 + 4 * G];
      const f32x4 Z3 = *(const f32x4*)&zS[p][r][48 + 4 * G];
      const float4 AL = *(const float4*)&aS[p][r][8 * G];
      const float4 AH = *(const float4*)&aS[p][r][8 * G + 4];
      const float GV = gS[p][r];

      const bf16x8 ab = cvt8f(AL, AH);
      f32x4 um[4];
#pragma unroll
      for (int m = 0; m < 4; ++m) {
        f32x4 acc = bias1[m];
        acc = __builtin_amdgcn_mfma_f32_16x16x32_bf16(w1h[m][0], hb0, acc, 0, 0, 0);
        acc = __builtin_amdgcn_mfma_f32_16x16x32_bf16(w1h[m][1], hb1, acc, 0, 0, 0);
        acc = __builtin_amdgcn_mfma_f32_16x16x32_bf16(w1a[m], ab, acc, 0, 0, 0);
        f32x4 u;
        u[0] = fast_tanh(acc[0]); u[1] = fast_tanh(acc[1]);
        u[2] = fast_tanh(acc[2]); u[3] = fast_tanh(acc[3]);
        um[m] = u;
      }
      const bf16x8 ub0 = cvt8(um[0], um[1]);
      const bf16x8 ub1 = cvt8(um[2], um[3]);
      const size_t ob = ((size_t)t * BB + row) * HID;
#pragma unroll
      for (int m = 0; m < 4; ++m) {
        f32x4 acc = bias2[m];
        acc = __builtin_amdgcn_mfma_f32_16x16x32_bf16(w2t[m][0], ub0, acc, 0, 0, 0);
        acc = __builtin_amdgcn_mfma_f32_16x16x32_bf16(w2t[m][1], ub1, acc, 0, 0, 0);
        const f32x4 zz = (m == 0) ? Z0 : (m == 1) ? Z1 : (m == 2) ? Z2 : Z3;
        f32x4 hn;
        hn[0] = fmaf(GV, fast_tanh(acc[0]) - zz[0], zz[0]);
        hn[1] = fmaf(GV, fast_tanh(acc[1]) - zz[1], zz[1]);
        hn[2] = fmaf(GV, fast_tanh(acc[2]) - zz[2], zz[2]);
        hn[3] = fmaf(GV, fast_tanh(acc[3]) - zz[3], zz[3]);
        hm[m] = hn;
        *(f32x4*)(outs + ob + 16 * m + 4 * G) = hn;
      }
      hb0 = cvt8(hm[0], hm[1]);
      hb1 = cvt8(hm[2], hm[3]);
    }
    lds_barrier();  // convergent: both waves, block scope
  }

  if (wid == 0) {
#pragma unroll
    for (int m = 0; m < 4; ++m)
      *(f32x4*)(hlast + (size_t)row * HID + 16 * m + 4 * G) = hm[m];
  }
}

extern "C" void kernel_launch(void* const* d_in, const int* in_sizes, int n_in,
                              void* d_out, int out_size, void* d_ws, size_t ws_size,
                              hipStream_t stream) {
  const float* x   = (const float*)d_in[0];
  const float* h0  = (const float*)d_in[1];
  const float* g   = (const float*)d_in[2];
  const float* a   = (const float*)d_in[3];
  const float* Wc1 = (const float*)d_in[4];
  const float* bc1 = (const float*)d_in[5];
  const float* Wc2 = (const float*)d_in[6];
  const float* bc2 = (const float*)d_in[7];
  const float* Wp1 = (const float*)d_in[8];
  const float* bp1 = (const float*)d_in[9];
  const float* Wp2 = (const float*)d_in[10];
  const float* bp2 = (const float*)d_in[11];

  float* out   = (float*)d_out;
  float* outs  = out;                                   // [T,B,H]
  float* hlast = out + (size_t)TT * BB * HID;           // [1,B,H]
  float* capt  = hlast + (size_t)BB * HID;              // [T,B,H]
  short* wsw   = (short*)d_ws;                          // 44 KB fragment buffer

  prep_weights<<<dim3(11), dim3(256), 0, stream>>>(Wc1, Wc2, Wp1, Wp2, wsw);
  capture_lds<<<dim3(2048), dim3(256), 0, stream>>>(x, wsw, bc1, bc2, capt);
  recur_pc3<<<dim3(BB / 16), dim3(128), 0, stream>>>(h0, g, a, Wp1, bp1, Wp2, bp2,
                                                     capt, outs, hlast);
}

// Round 23
// 216.952 us; speedup vs baseline: 1.2296x; 1.2296x over previous
//
#include <hip/hip_runtime.h>

#define OBS 128
#define HID 64
#define ACT 32
#define TT  128
#define BB  4096

typedef __attribute__((ext_vector_type(8))) short bf16x8;  // 8 bf16 (4 VGPRs)
typedef __attribute__((ext_vector_type(4))) float f32x4;

// tanh(v) = 1 - 2/(exp(2v)+1); exact at +-inf, ~1e-6 rel error (v_exp + v_rcp)
__device__ __forceinline__ float fast_tanh(float v) {
  const float e = __expf(2.0f * v);
  return 1.0f - 2.0f * __builtin_amdgcn_rcpf(e + 1.0f);
}

// Pade(7,6) tanh: x(945+105x^2+x^4)/(945+420x^2+15x^4), clamped to +-1.
// Max error <= ~7e-4 over all x (checked 0.5..6); 1 trans op (rcp) instead of
// 2 (exp+rcp) -> halves the consumer's per-step transcendental issue cost.
__device__ __forceinline__ float pade_tanh(float x) {
  const float x2 = x * x;
  const float num = x * fmaf(x2, fmaf(x2, 1.0f, 105.0f), 945.0f);
  const float den = fmaf(x2, fmaf(x2, 15.0f, 420.0f), 945.0f);
  const float t = num * __builtin_amdgcn_rcpf(den);
  return fminf(1.0f, fmaxf(-1.0f, t));
}

// f32 -> bf16 bits, round-to-nearest-even (prep + capture paths)
__device__ __forceinline__ short f2bf(float f) {
  const unsigned u = __float_as_uint(f);
  return (short)((u + 0x7FFFu + ((u >> 16) & 1u)) >> 16);
}

// HW packed f32x2 -> bf16x2 (RNE), gfx950; no builtin -> inline asm (T12/m240).
__device__ __forceinline__ unsigned cvtpk(float lo, float hi) {
  unsigned r;
  asm("v_cvt_pk_bf16_f32 %0, %1, %2" : "=v"(r) : "v"(lo), "v"(hi));
  return r;
}

// pack two f32x4 (C/D-layout quads) into one bf16x8 B-fragment (4 instrs)
__device__ __forceinline__ bf16x8 cvt8(const f32x4 s0, const f32x4 s1) {
  union { bf16x8 f; unsigned u[4]; } z;
  z.u[0] = cvtpk(s0[0], s0[1]); z.u[1] = cvtpk(s0[2], s0[3]);
  z.u[2] = cvtpk(s1[0], s1[1]); z.u[3] = cvtpk(s1[2], s1[3]);
  return z.f;
}

// pack [float4, float4] -> bf16x8
__device__ __forceinline__ bf16x8 cvt8f(const float4 lo, const float4 hi) {
  union { bf16x8 f; unsigned u[4]; } z;
  z.u[0] = cvtpk(lo.x, lo.y); z.u[1] = cvtpk(lo.z, lo.w);
  z.u[2] = cvtpk(hi.x, hi.y); z.u[3] = cvtpk(hi.z, hi.w);
  return z.f;
}

// LDS barrier: drain own ds ops, sync waves (NOT __syncthreads — no vmcnt drain)
__device__ __forceinline__ void lds_barrier() {
  asm volatile("s_waitcnt lgkmcnt(0)" ::: "memory");
  __builtin_amdgcn_s_barrier();
  asm volatile("" ::: "memory");
}

// ---------------------------------------------------------------------------
// Prep: fragment-ordered bf16 weight table in d_ws (capture uses frags 0..23;
// recur consumer gathers Wp1/Wp2 directly).
// ---------------------------------------------------------------------------
__global__ void prep_weights(const float* __restrict__ Wc1,
                             const float* __restrict__ Wc2,
                             const float* __restrict__ Wp1,
                             const float* __restrict__ Wp2,
                             short* __restrict__ ws)
{
  const int idx = blockIdx.x * blockDim.x + threadIdx.x;  // 0..(44*64-1)
  if (idx >= 44 * 64) return;
  const int f = idx >> 6, lane = idx & 63;
  const int r = lane & 15, G = lane >> 4;
  short o[8];
  if (f < 16) {
    const int m = f >> 2, kk = f & 3;  // std: k = 32kk + 8G + j
#pragma unroll
    for (int j = 0; j < 8; ++j)
      o[j] = f2bf(Wc1[(kk * 32 + 8 * G + j) * HID + 16 * m + r]);
  } else if (f < 40) {
    const int q = (f < 24) ? (f - 16) : (f < 32) ? (f - 24) : (f - 32);
    const float* W = (f < 24) ? Wc2 : (f < 32) ? Wp1 : Wp2;
    const int m = q >> 1, kk = q & 1;  // custom k-map (matches lane-resident C/D)
#pragma unroll
    for (int j = 0; j < 8; ++j) {
      const int k = (j < 4) ? (32 * kk + 4 * G + j)
                            : (32 * kk + 16 + 4 * G + (j - 4));
      o[j] = f2bf(W[k * HID + 16 * m + r]);
    }
  } else {
    const int m = f - 40;  // a-part, std map: k = HID + 8G + j
#pragma unroll
    for (int j = 0; j < 8; ++j)
      o[j] = f2bf(Wp1[(HID + 8 * G + j) * HID + 16 * m + r]);
  }
  bf16x8 v;
#pragma unroll
  for (int j = 0; j < 8; ++j) v[j] = o[j];
  *(bf16x8*)(ws + (size_t)idx * 8) = v;
}

// ---------------------------------------------------------------------------
// Phase 1: capture — BYTE-IDENTICAL to rounds 9..17 (deterministic LDS-weight
// form, HBM-bound ~65-75 us at 2 blocks/CU). exp-based tanh retained here.
// ---------------------------------------------------------------------------
__global__ __launch_bounds__(256, 2) void capture_lds(
    const float* __restrict__ x,
    const short* __restrict__ wsw,
    const float* __restrict__ bc1, const float* __restrict__ bc2,
    float* __restrict__ capt)
{
  __shared__ bf16x8 wl[24 * 64];  // 24.5 KB fragment table

  const int tid  = threadIdx.x;
  const int lane = tid & 63;
  const int r    = lane & 15;   // tile-row (N dim)
  const int G    = lane >> 4;   // k-group
  const int wave = blockIdx.x * 4 + (tid >> 6);
  const int nwaves = gridDim.x * 4;

  for (int s = tid; s < 24 * 64; s += 256)
    wl[s] = ((const bf16x8*)wsw)[s];
  __syncthreads();

  f32x4 bias1[4], bias2[4];
#pragma unroll
  for (int m = 0; m < 4; ++m) {
    bias1[m] = *(const f32x4*)(bc1 + 16 * m + 4 * G);
    bias2[m] = *(const f32x4*)(bc2 + 16 * m + 4 * G);
  }

  for (int tile = wave; tile < (TT * BB) / 16; tile += nwaves) {
    asm volatile("" ::: "memory");

    const float* xrow = x + ((size_t)tile * 16 + r) * OBS;
    bf16x8 xa[4];
#pragma unroll
    for (int kk = 0; kk < 4; ++kk) {
      const float4 lo = *(const float4*)(xrow + kk * 32 + 8 * G);
      const float4 hi = *(const float4*)(xrow + kk * 32 + 8 * G + 4);
      bf16x8 f;
      f[0] = f2bf(lo.x); f[1] = f2bf(lo.y); f[2] = f2bf(lo.z); f[3] = f2bf(lo.w);
      f[4] = f2bf(hi.x); f[5] = f2bf(hi.y); f[6] = f2bf(hi.z); f[7] = f2bf(hi.w);
      xa[kk] = f;
    }

    float um[4][4];
#pragma unroll
    for (int m = 0; m < 4; ++m) {
      f32x4 acc = bias1[m];
#pragma unroll
      for (int kk = 0; kk < 4; ++kk)
        acc = __builtin_amdgcn_mfma_f32_16x16x32_bf16(wl[(m * 4 + kk) * 64 + lane],
                                                      xa[kk], acc, 0, 0, 0);
#pragma unroll
      for (int q = 0; q < 4; ++q) um[m][q] = fast_tanh(acc[q]);
    }

    bf16x8 b2[2];
#pragma unroll
    for (int kk = 0; kk < 2; ++kk) {
      bf16x8 f;
#pragma unroll
      for (int j = 0; j < 4; ++j) f[j]     = f2bf(um[2 * kk][j]);
#pragma unroll
      for (int j = 0; j < 4; ++j) f[4 + j] = f2bf(um[2 * kk + 1][j]);
      b2[kk] = f;
    }

    float* crow = capt + ((size_t)tile * 16 + r) * HID;
#pragma unroll
    for (int m = 0; m < 4; ++m) {
      f32x4 acc = bias2[m];
#pragma unroll
      for (int kk = 0; kk < 2; ++kk)
        acc = __builtin_amdgcn_mfma_f32_16x16x32_bf16(wl[(16 + m * 2 + kk) * 64 + lane],
                                                      b2[kk], acc, 0, 0, 0);
      float4 o;
      o.x = fast_tanh(acc[0]); o.y = fast_tanh(acc[1]);
      o.z = fast_tanh(acc[2]); o.w = fast_tanh(acc[3]);
      *(float4*)(crow + 16 * m + 4 * G) = o;
    }
  }
}

// ---------------------------------------------------------------------------
// Phase 2: recurrence — r17-VERBATIM structure (best measured: 204 us total,
// validated pass; divergent per-role loops give each role its OWN register
// allocation — r21/r22's convergent skeleton forced a union live-set and
// spilled, 147/199 us). ONE change: consumer tanh -> pade_tanh (halves the
// ~512 cyc/step transcendental issue that sits on the serial h-chain).
// Grid: 256 blocks x 128 threads (1 block/CU; 2 waves).
// ---------------------------------------------------------------------------
__global__ __launch_bounds__(128, 1) void recur_pc(
    const float* __restrict__ h0,
    const float* __restrict__ g,
    const float* __restrict__ a,
    const float* __restrict__ Wp1, const float* __restrict__ bp1,
    const float* __restrict__ Wp2, const float* __restrict__ bp2,
    const float* __restrict__ z1buf,
    float* __restrict__ outs, float* __restrict__ hlast)
{
  __shared__ float zS[2][16][68];  // z slot: 16 rows x 64 (+4 pad)
  __shared__ float aS[2][16][36];  // a slot: 16 rows x 32 (+4 pad)
  __shared__ float gS[2][16];

  const int tid  = threadIdx.x;
  const int lane = tid & 63;
  const int wid  = __builtin_amdgcn_readfirstlane(tid >> 6);
  const int row0 = blockIdx.x * 16;

  if (wid == 1) {
    // ================= PRODUCER =================
#define P_STAGE(t, p)                                                       \
    do {                                                                    \
      const size_t rb = (size_t)(t) * BB + row0;                            \
      const float* zp = z1buf + rb * HID;                                   \
      float4 zv[4];                                                         \
      _Pragma("unroll")                                                     \
      for (int i = 0; i < 4; ++i)                                           \
        zv[i] = *(const float4*)(zp + i * 256 + lane * 4);                  \
      const float* ap = a + rb * ACT;                                       \
      float4 av[2];                                                         \
      _Pragma("unroll")                                                     \
      for (int i = 0; i < 2; ++i)                                           \
        av[i] = *(const float4*)(ap + i * 256 + lane * 4);                  \
      float gv = 0.0f;                                                      \
      if (lane < 16) gv = g[rb + lane];                                     \
      _Pragma("unroll")                                                     \
      for (int i = 0; i < 4; ++i) {                                         \
        const int rr = i * 4 + (lane >> 4), cc = (lane & 15) * 4;           \
        *(float4*)&zS[p][rr][cc] = zv[i];                                   \
      }                                                                     \
      _Pragma("unroll")                                                     \
      for (int i = 0; i < 2; ++i) {                                         \
        const int rr = i * 8 + (lane >> 3), cc = (lane & 7) * 4;            \
        *(float4*)&aS[p][rr][cc] = av[i];                                   \
      }                                                                     \
      if (lane < 16) gS[p][lane] = gv;                                      \
    } while (0)

    P_STAGE(0, 0);
    lds_barrier();
    for (int t = 0; t < TT; ++t) {
      const int tn = (t + 1 < TT) ? (t + 1) : (TT - 1);  // clamp
      P_STAGE(tn, (t + 1) & 1);
      lds_barrier();
    }
  } else {
    // ================= CONSUMER =================
    const int r = lane & 15;
    const int G = lane >> 4;
    const int row = row0 + r;

    // weights gathered once; in-loop pin keeps them resident (r15)
    bf16x8 w1h[4][2], w2t[4][2], w1a[4];
#pragma unroll
    for (int m = 0; m < 4; ++m) {
#pragma unroll
      for (int kk = 0; kk < 2; ++kk) {
        bf16x8 f1, f2;
#pragma unroll
        for (int j = 0; j < 8; ++j) {
          const int k = (j < 4) ? (32 * kk + 4 * G + j)
                                : (32 * kk + 16 + 4 * G + (j - 4));
          f1[j] = f2bf(Wp1[k * HID + 16 * m + r]);
          f2[j] = f2bf(Wp2[k * HID + 16 * m + r]);
        }
        w1h[m][kk] = f1;
        w2t[m][kk] = f2;
      }
      bf16x8 fa;  // a-part, std map: k = HID + 8G + j
#pragma unroll
      for (int j = 0; j < 8; ++j)
        fa[j] = f2bf(Wp1[(HID + 8 * G + j) * HID + 16 * m + r]);
      w1a[m] = fa;
    }
    f32x4 bias1[4], bias2[4];
#pragma unroll
    for (int m = 0; m < 4; ++m) {
      bias1[m] = *(const f32x4*)(bp1 + 16 * m + 4 * G);
      bias2[m] = *(const f32x4*)(bp2 + 16 * m + 4 * G);
    }

    f32x4 hm[4];
#pragma unroll
    for (int m = 0; m < 4; ++m)
      hm[m] = *(const f32x4*)(h0 + (size_t)row * HID + 16 * m + 4 * G);
    bf16x8 hb0 = cvt8(hm[0], hm[1]);
    bf16x8 hb1 = cvt8(hm[2], hm[3]);

    lds_barrier();  // matches producer's initial-fill barrier

    for (int t = 0; t < TT; ++t) {
      // in-loop pin: weights/biases are loop-carried opaque values
#pragma unroll
      for (int m = 0; m < 4; ++m) {
        asm volatile("" : "+v"(w1h[m][0]), "+v"(w1h[m][1]));
        asm volatile("" : "+v"(w2t[m][0]), "+v"(w2t[m][1]));
        asm volatile("" : "+v"(w1a[m]));
        asm volatile("" : "+v"(bias1[m]), "+v"(bias2[m]));
      }

      const int p = t & 1;
      const f32x4 Z0 = *(const f32x4*)&zS[p][r][4 * G];
      const f32x4 Z1 = *(const f32x4*)&zS[p][r][16 + 4 * G];
      const f32x4 Z2 = *(const f32x4*)&zS[p][r][32 + 4 * G];
      const f32x4 Z3 = *(const f32x4*)&zS[p][r][48 + 4 * G];
      const float4 AL = *(const float4*)&aS[p][r][8 * G];
      const float4 AH = *(const float4*)&aS[p][r][8 * G + 4];
      const float GV = gS[p][r];

      const bf16x8 ab = cvt8f(AL, AH);
      f32x4 um[4];
#pragma unroll
      for (int m = 0; m < 4; ++m) {
        f32x4 acc = bias1[m];
        acc = __builtin_amdgcn_mfma_f32_16x16x32_bf16(w1h[m][0], hb0, acc, 0, 0, 0);
        acc = __builtin_amdgcn_mfma_f32_16x16x32_bf16(w1h[m][1], hb1, acc, 0, 0, 0);
        acc = __builtin_amdgcn_mfma_f32_16x16x32_bf16(w1a[m], ab, acc, 0, 0, 0);
        f32x4 u;
        u[0] = pade_tanh(acc[0]); u[1] = pade_tanh(acc[1]);
        u[2] = pade_tanh(acc[2]); u[3] = pade_tanh(acc[3]);
        um[m] = u;
      }
      const bf16x8 ub0 = cvt8(um[0], um[1]);
      const bf16x8 ub1 = cvt8(um[2], um[3]);
      const size_t ob = ((size_t)t * BB + row) * HID;
#pragma unroll
      for (int m = 0; m < 4; ++m) {
        f32x4 acc = bias2[m];
        acc = __builtin_amdgcn_mfma_f32_16x16x32_bf16(w2t[m][0], ub0, acc, 0, 0, 0);
        acc = __builtin_amdgcn_mfma_f32_16x16x32_bf16(w2t[m][1], ub1, acc, 0, 0, 0);
        const f32x4 zz = (m == 0) ? Z0 : (m == 1) ? Z1 : (m == 2) ? Z2 : Z3;
        f32x4 hn;
        hn[0] = fmaf(GV, pade_tanh(acc[0]) - zz[0], zz[0]);
        hn[1] = fmaf(GV, pade_tanh(acc[1]) - zz[1], zz[1]);
        hn[2] = fmaf(GV, pade_tanh(acc[2]) - zz[2], zz[2]);
        hn[3] = fmaf(GV, pade_tanh(acc[3]) - zz[3], zz[3]);
        hm[m] = hn;
        *(f32x4*)(outs + ob + 16 * m + 4 * G) = hn;
      }
      hb0 = cvt8(hm[0], hm[1]);
      hb1 = cvt8(hm[2], hm[3]);

      lds_barrier();
    }

#pragma unroll
    for (int m = 0; m < 4; ++m)
      *(f32x4*)(hlast + (size_t)row * HID + 16 * m + 4 * G) = hm[m];
  }
}

extern "C" void kernel_launch(void* const* d_in, const int* in_sizes, int n_in,
                              void* d_out, int out_size, void* d_ws, size_t ws_size,
                              hipStream_t stream) {
  const float* x   = (const float*)d_in[0];
  const float* h0  = (const float*)d_in[1];
  const float* g   = (const float*)d_in[2];
  const float* a   = (const float*)d_in[3];
  const float* Wc1 = (const float*)d_in[4];
  const float* bc1 = (const float*)d_in[5];
  const float* Wc2 = (const float*)d_in[6];
  const float* bc2 = (const float*)d_in[7];
  const float* Wp1 = (const float*)d_in[8];
  const float* bp1 = (const float*)d_in[9];
  const float* Wp2 = (const float*)d_in[10];
  const float* bp2 = (const float*)d_in[11];

  float* out   = (float*)d_out;
  float* outs  = out;                                   // [T,B,H]
  float* hlast = out + (size_t)TT * BB * HID;           // [1,B,H]
  float* capt  = hlast + (size_t)BB * HID;              // [T,B,H]
  short* wsw   = (short*)d_ws;                          // 44 KB fragment buffer

  prep_weights<<<dim3(11), dim3(256), 0, stream>>>(Wc1, Wc2, Wp1, Wp2, wsw);
  capture_lds<<<dim3(2048), dim3(256), 0, stream>>>(x, wsw, bc1, bc2, capt);
  recur_pc<<<dim3(BB / 16), dim3(128), 0, stream>>>(h0, g, a, Wp1, bp1, Wp2, bp2,
                                                    capt, outs, hlast);
}

// Round 24
// 201.069 us; speedup vs baseline: 1.3267x; 1.0790x over previous
//
#include <hip/hip_runtime.h>

#define OBS 128
#define HID 64
#define ACT 32
#define TT  128
#define BB  4096

typedef __attribute__((ext_vector_type(8))) short bf16x8;  // 8 bf16 (4 VGPRs)
typedef __attribute__((ext_vector_type(4))) float f32x4;

// tanh(v) = 1 - 2/(exp(2v)+1); exact at +-inf, ~1e-6 rel error (v_exp + v_rcp)
__device__ __forceinline__ float fast_tanh(float v) {
  const float e = __expf(2.0f * v);
  return 1.0f - 2.0f * __builtin_amdgcn_rcpf(e + 1.0f);
}

// f32 -> bf16 bits, round-to-nearest-even (prep + capture paths)
__device__ __forceinline__ short f2bf(float f) {
  const unsigned u = __float_as_uint(f);
  return (short)((u + 0x7FFFu + ((u >> 16) & 1u)) >> 16);
}

// HW packed f32x2 -> bf16x2 (RNE), gfx950; no builtin -> inline asm (T12/m240).
__device__ __forceinline__ unsigned cvtpk(float lo, float hi) {
  unsigned r;
  asm("v_cvt_pk_bf16_f32 %0, %1, %2" : "=v"(r) : "v"(lo), "v"(hi));
  return r;
}

// pack two f32x4 (C/D-layout quads) into one bf16x8 B-fragment (4 instrs)
__device__ __forceinline__ bf16x8 cvt8(const f32x4 s0, const f32x4 s1) {
  union { bf16x8 f; unsigned u[4]; } z;
  z.u[0] = cvtpk(s0[0], s0[1]); z.u[1] = cvtpk(s0[2], s0[3]);
  z.u[2] = cvtpk(s1[0], s1[1]); z.u[3] = cvtpk(s1[2], s1[3]);
  return z.f;
}

// pack [float4, float4] -> bf16x8
__device__ __forceinline__ bf16x8 cvt8f(const float4 lo, const float4 hi) {
  union { bf16x8 f; unsigned u[4]; } z;
  z.u[0] = cvtpk(lo.x, lo.y); z.u[1] = cvtpk(lo.z, lo.w);
  z.u[2] = cvtpk(hi.x, hi.y); z.u[3] = cvtpk(hi.z, hi.w);
  return z.f;
}

// LDS barrier: drain own ds ops, sync waves (NOT __syncthreads — no vmcnt drain)
__device__ __forceinline__ void lds_barrier() {
  asm volatile("s_waitcnt lgkmcnt(0)" ::: "memory");
  __builtin_amdgcn_s_barrier();
  asm volatile("" ::: "memory");
}

// ---------------------------------------------------------------------------
// Prep: fragment-ordered bf16 weight table in d_ws (capture uses frags 0..23;
// recur consumer gathers Wp1/Wp2 directly).
// ---------------------------------------------------------------------------
__global__ void prep_weights(const float* __restrict__ Wc1,
                             const float* __restrict__ Wc2,
                             const float* __restrict__ Wp1,
                             const float* __restrict__ Wp2,
                             short* __restrict__ ws)
{
  const int idx = blockIdx.x * blockDim.x + threadIdx.x;  // 0..(44*64-1)
  if (idx >= 44 * 64) return;
  const int f = idx >> 6, lane = idx & 63;
  const int r = lane & 15, G = lane >> 4;
  short o[8];
  if (f < 16) {
    const int m = f >> 2, kk = f & 3;  // std: k = 32kk + 8G + j
#pragma unroll
    for (int j = 0; j < 8; ++j)
      o[j] = f2bf(Wc1[(kk * 32 + 8 * G + j) * HID + 16 * m + r]);
  } else if (f < 40) {
    const int q = (f < 24) ? (f - 16) : (f < 32) ? (f - 24) : (f - 32);
    const float* W = (f < 24) ? Wc2 : (f < 32) ? Wp1 : Wp2;
    const int m = q >> 1, kk = q & 1;  // custom k-map (matches lane-resident C/D)
#pragma unroll
    for (int j = 0; j < 8; ++j) {
      const int k = (j < 4) ? (32 * kk + 4 * G + j)
                            : (32 * kk + 16 + 4 * G + (j - 4));
      o[j] = f2bf(W[k * HID + 16 * m + r]);
    }
  } else {
    const int m = f - 40;  // a-part, std map: k = HID + 8G + j
#pragma unroll
    for (int j = 0; j < 8; ++j)
      o[j] = f2bf(Wp1[(HID + 8 * G + j) * HID + 16 * m + r]);
  }
  bf16x8 v;
#pragma unroll
  for (int j = 0; j < 8; ++j) v[j] = o[j];
  *(bf16x8*)(ws + (size_t)idx * 8) = v;
}

// ---------------------------------------------------------------------------
// Phase 1: capture — BYTE-IDENTICAL to rounds 9..23 (deterministic LDS-weight
// form, HBM-bound ~65-75 us at 2 blocks/CU).
// ---------------------------------------------------------------------------
__global__ __launch_bounds__(256, 2) void capture_lds(
    const float* __restrict__ x,
    const short* __restrict__ wsw,
    const float* __restrict__ bc1, const float* __restrict__ bc2,
    float* __restrict__ capt)
{
  __shared__ bf16x8 wl[24 * 64];  // 24.5 KB fragment table

  const int tid  = threadIdx.x;
  const int lane = tid & 63;
  const int r    = lane & 15;   // tile-row (N dim)
  const int G    = lane >> 4;   // k-group
  const int wave = blockIdx.x * 4 + (tid >> 6);
  const int nwaves = gridDim.x * 4;

  for (int s = tid; s < 24 * 64; s += 256)
    wl[s] = ((const bf16x8*)wsw)[s];
  __syncthreads();

  f32x4 bias1[4], bias2[4];
#pragma unroll
  for (int m = 0; m < 4; ++m) {
    bias1[m] = *(const f32x4*)(bc1 + 16 * m + 4 * G);
    bias2[m] = *(const f32x4*)(bc2 + 16 * m + 4 * G);
  }

  for (int tile = wave; tile < (TT * BB) / 16; tile += nwaves) {
    asm volatile("" ::: "memory");

    const float* xrow = x + ((size_t)tile * 16 + r) * OBS;
    bf16x8 xa[4];
#pragma unroll
    for (int kk = 0; kk < 4; ++kk) {
      const float4 lo = *(const float4*)(xrow + kk * 32 + 8 * G);
      const float4 hi = *(const float4*)(xrow + kk * 32 + 8 * G + 4);
      bf16x8 f;
      f[0] = f2bf(lo.x); f[1] = f2bf(lo.y); f[2] = f2bf(lo.z); f[3] = f2bf(lo.w);
      f[4] = f2bf(hi.x); f[5] = f2bf(hi.y); f[6] = f2bf(hi.z); f[7] = f2bf(hi.w);
      xa[kk] = f;
    }

    float um[4][4];
#pragma unroll
    for (int m = 0; m < 4; ++m) {
      f32x4 acc = bias1[m];
#pragma unroll
      for (int kk = 0; kk < 4; ++kk)
        acc = __builtin_amdgcn_mfma_f32_16x16x32_bf16(wl[(m * 4 + kk) * 64 + lane],
                                                      xa[kk], acc, 0, 0, 0);
#pragma unroll
      for (int q = 0; q < 4; ++q) um[m][q] = fast_tanh(acc[q]);
    }

    bf16x8 b2[2];
#pragma unroll
    for (int kk = 0; kk < 2; ++kk) {
      bf16x8 f;
#pragma unroll
      for (int j = 0; j < 4; ++j) f[j]     = f2bf(um[2 * kk][j]);
#pragma unroll
      for (int j = 0; j < 4; ++j) f[4 + j] = f2bf(um[2 * kk + 1][j]);
      b2[kk] = f;
    }

    float* crow = capt + ((size_t)tile * 16 + r) * HID;
#pragma unroll
    for (int m = 0; m < 4; ++m) {
      f32x4 acc = bias2[m];
#pragma unroll
      for (int kk = 0; kk < 2; ++kk)
        acc = __builtin_amdgcn_mfma_f32_16x16x32_bf16(wl[(16 + m * 2 + kk) * 64 + lane],
                                                      b2[kk], acc, 0, 0, 0);
      float4 o;
      o.x = fast_tanh(acc[0]); o.y = fast_tanh(acc[1]);
      o.z = fast_tanh(acc[2]); o.w = fast_tanh(acc[3]);
      *(float4*)(crow + 16 * m + 4 * G) = o;
    }
  }
}

// ---------------------------------------------------------------------------
// Phase 2: recurrence — r17 structure (divergent per-role allocation, exp
// tanh, pinned weights) with ONE change: 2 STEPS PER BARRIER PHASE on a
// 4-slot ring. Producer stages steps {2k+2,2k+3} while consumer computes
// {2k,2k+1}; slot parity (k even: cons 0,1 / prod 2,3; k odd: swapped)
// guarantees no overlap. Barriers drop 256 -> 130 and the scheduler can
// overlap step 2k+1's LDS reads under step 2k's chain.
// Grid: 256 blocks x 128 threads (1 block/CU; 2 waves).
// ---------------------------------------------------------------------------
__global__ __launch_bounds__(128, 1) void recur_pc(
    const float* __restrict__ h0,
    const float* __restrict__ g,
    const float* __restrict__ a,
    const float* __restrict__ Wp1, const float* __restrict__ bp1,
    const float* __restrict__ Wp2, const float* __restrict__ bp2,
    const float* __restrict__ z1buf,
    float* __restrict__ outs, float* __restrict__ hlast)
{
  __shared__ float zS[4][16][68];  // z slot: 16 rows x 64 (+4 pad)
  __shared__ float aS[4][16][36];  // a slot: 16 rows x 32 (+4 pad)
  __shared__ float gS[4][16];

  const int tid  = threadIdx.x;
  const int lane = tid & 63;
  const int wid  = __builtin_amdgcn_readfirstlane(tid >> 6);
  const int row0 = blockIdx.x * 16;

  if (wid == 1) {
    // ================= PRODUCER =================
#define P_STAGE(t, p)                                                       \
    do {                                                                    \
      const size_t rb = (size_t)(t) * BB + row0;                            \
      const float* zp = z1buf + rb * HID;                                   \
      float4 zv[4];                                                         \
      _Pragma("unroll")                                                     \
      for (int i = 0; i < 4; ++i)                                           \
        zv[i] = *(const float4*)(zp + i * 256 + lane * 4);                  \
      const float* ap = a + rb * ACT;                                       \
      float4 av[2];                                                         \
      _Pragma("unroll")                                                     \
      for (int i = 0; i < 2; ++i)                                           \
        av[i] = *(const float4*)(ap + i * 256 + lane * 4);                  \
      float gv = 0.0f;                                                      \
      if (lane < 16) gv = g[rb + lane];                                     \
      _Pragma("unroll")                                                     \
      for (int i = 0; i < 4; ++i) {                                         \
        const int rr = i * 4 + (lane >> 4), cc = (lane & 15) * 4;           \
        *(float4*)&zS[p][rr][cc] = zv[i];                                   \
      }                                                                     \
      _Pragma("unroll")                                                     \
      for (int i = 0; i < 2; ++i) {                                         \
        const int rr = i * 8 + (lane >> 3), cc = (lane & 7) * 4;            \
        *(float4*)&aS[p][rr][cc] = av[i];                                   \
      }                                                                     \
      if (lane < 16) gS[p][lane] = gv;                                      \
    } while (0)

    P_STAGE(0, 0);
    P_STAGE(1, 1);
    lds_barrier();
    for (int k = 0; k < TT / 2; ++k) {
      const int t2 = (2 * k + 2 < TT) ? (2 * k + 2) : (TT - 1);  // clamp
      const int t3 = (2 * k + 3 < TT) ? (2 * k + 3) : (TT - 1);
      P_STAGE(t2, (2 * k + 2) & 3);
      P_STAGE(t3, (2 * k + 3) & 3);
      lds_barrier();
    }
  } else {
    // ================= CONSUMER =================
    const int r = lane & 15;
    const int G = lane >> 4;
    const int row = row0 + r;

    // weights gathered once; in-loop pin keeps them resident (r15)
    bf16x8 w1h[4][2], w2t[4][2], w1a[4];
#pragma unroll
    for (int m = 0; m < 4; ++m) {
#pragma unroll
      for (int kk = 0; kk < 2; ++kk) {
        bf16x8 f1, f2;
#pragma unroll
        for (int j = 0; j < 8; ++j) {
          const int k = (j < 4) ? (32 * kk + 4 * G + j)
                                : (32 * kk + 16 + 4 * G + (j - 4));
          f1[j] = f2bf(Wp1[k * HID + 16 * m + r]);
          f2[j] = f2bf(Wp2[k * HID + 16 * m + r]);
        }
        w1h[m][kk] = f1;
        w2t[m][kk] = f2;
      }
      bf16x8 fa;  // a-part, std map: k = HID + 8G + j
#pragma unroll
      for (int j = 0; j < 8; ++j)
        fa[j] = f2bf(Wp1[(HID + 8 * G + j) * HID + 16 * m + r]);
      w1a[m] = fa;
    }
    f32x4 bias1[4], bias2[4];
#pragma unroll
    for (int m = 0; m < 4; ++m) {
      bias1[m] = *(const f32x4*)(bp1 + 16 * m + 4 * G);
      bias2[m] = *(const f32x4*)(bp2 + 16 * m + 4 * G);
    }

    f32x4 hm[4];
#pragma unroll
    for (int m = 0; m < 4; ++m)
      hm[m] = *(const f32x4*)(h0 + (size_t)row * HID + 16 * m + 4 * G);
    bf16x8 hb0 = cvt8(hm[0], hm[1]);
    bf16x8 hb1 = cvt8(hm[2], hm[3]);

    lds_barrier();  // matches producer's initial-fill barrier

#define C_STEP(t)                                                              \
    do {                                                                       \
      const int p = (t) & 3;                                                   \
      const f32x4 Z0 = *(const f32x4*)&zS[p][r][4 * G];                        \
      const f32x4 Z1 = *(const f32x4*)&zS[p][r][16 + 4 * G];                   \
      const f32x4 Z2 = *(const f32x4*)&zS[p][r][32 + 4 * G];                   \
      const f32x4 Z3 = *(const f32x4*)&zS[p][r][48 + 4 * G];                   \
      const float4 AL = *(const float4*)&aS[p][r][8 * G];                      \
      const float4 AH = *(const float4*)&aS[p][r][8 * G + 4];                  \
      const float GV = gS[p][r];                                               \
      const bf16x8 ab = cvt8f(AL, AH);                                         \
      f32x4 um[4];                                                             \
      _Pragma("unroll")                                                        \
      for (int m = 0; m < 4; ++m) {                                            \
        f32x4 acc = bias1[m];                                                  \
        acc = __builtin_amdgcn_mfma_f32_16x16x32_bf16(w1h[m][0], hb0, acc, 0, 0, 0); \
        acc = __builtin_amdgcn_mfma_f32_16x16x32_bf16(w1h[m][1], hb1, acc, 0, 0, 0); \
        acc = __builtin_amdgcn_mfma_f32_16x16x32_bf16(w1a[m], ab, acc, 0, 0, 0); \
        f32x4 u;                                                               \
        u[0] = fast_tanh(acc[0]); u[1] = fast_tanh(acc[1]);                    \
        u[2] = fast_tanh(acc[2]); u[3] = fast_tanh(acc[3]);                    \
        um[m] = u;                                                             \
      }                                                                        \
      const bf16x8 ub0 = cvt8(um[0], um[1]);                                   \
      const bf16x8 ub1 = cvt8(um[2], um[3]);                                   \
      const size_t ob = ((size_t)(t) * BB + row) * HID;                        \
      _Pragma("unroll")                                                        \
      for (int m = 0; m < 4; ++m) {                                            \
        f32x4 acc = bias2[m];                                                  \
        acc = __builtin_amdgcn_mfma_f32_16x16x32_bf16(w2t[m][0], ub0, acc, 0, 0, 0); \
        acc = __builtin_amdgcn_mfma_f32_16x16x32_bf16(w2t[m][1], ub1, acc, 0, 0, 0); \
        const f32x4 zz = (m == 0) ? Z0 : (m == 1) ? Z1 : (m == 2) ? Z2 : Z3;   \
        f32x4 hn;                                                              \
        hn[0] = fmaf(GV, fast_tanh(acc[0]) - zz[0], zz[0]);                    \
        hn[1] = fmaf(GV, fast_tanh(acc[1]) - zz[1], zz[1]);                    \
        hn[2] = fmaf(GV, fast_tanh(acc[2]) - zz[2], zz[2]);                    \
        hn[3] = fmaf(GV, fast_tanh(acc[3]) - zz[3], zz[3]);                    \
        hm[m] = hn;                                                            \
        *(f32x4*)(outs + ob + 16 * m + 4 * G) = hn;                            \
      }                                                                        \
      hb0 = cvt8(hm[0], hm[1]);                                                \
      hb1 = cvt8(hm[2], hm[3]);                                                \
    } while (0)

    for (int k = 0; k < TT / 2; ++k) {
      // in-loop pin: weights/biases are loop-carried opaque values
#pragma unroll
      for (int m = 0; m < 4; ++m) {
        asm volatile("" : "+v"(w1h[m][0]), "+v"(w1h[m][1]));
        asm volatile("" : "+v"(w2t[m][0]), "+v"(w2t[m][1]));
        asm volatile("" : "+v"(w1a[m]));
        asm volatile("" : "+v"(bias1[m]), "+v"(bias2[m]));
      }

      C_STEP(2 * k);
      C_STEP(2 * k + 1);
      lds_barrier();
    }

#pragma unroll
    for (int m = 0; m < 4; ++m)
      *(f32x4*)(hlast + (size_t)row * HID + 16 * m + 4 * G) = hm[m];
  }
}

extern "C" void kernel_launch(void* const* d_in, const int* in_sizes, int n_in,
                              void* d_out, int out_size, void* d_ws, size_t ws_size,
                              hipStream_t stream) {
  const float* x   = (const float*)d_in[0];
  const float* h0  = (const float*)d_in[1];
  const float* g   = (const float*)d_in[2];
  const float* a   = (const float*)d_in[3];
  const float* Wc1 = (const float*)d_in[4];
  const float* bc1 = (const float*)d_in[5];
  const float* Wc2 = (const float*)d_in[6];
  const float* bc2 = (const float*)d_in[7];
  const float* Wp1 = (const float*)d_in[8];
  const float* bp1 = (const float*)d_in[9];
  const float* Wp2 = (const float*)d_in[10];
  const float* bp2 = (const float*)d_in[11];

  float* out   = (float*)d_out;
  float* outs  = out;                                   // [T,B,H]
  float* hlast = out + (size_t)TT * BB * HID;           // [1,B,H]
  float* capt  = hlast + (size_t)BB * HID;              // [T,B,H]
  short* wsw   = (short*)d_ws;                          // 44 KB fragment buffer

  prep_weights<<<dim3(11), dim3(256), 0, stream>>>(Wc1, Wc2, Wp1, Wp2, wsw);
  capture_lds<<<dim3(2048), dim3(256), 0, stream>>>(x, wsw, bc1, bc2, capt);
  recur_pc<<<dim3(BB / 16), dim3(128), 0, stream>>>(h0, g, a, Wp1, bp1, Wp2, bp2,
                                                    capt, outs, hlast);
}

// Round 25
// 199.687 us; speedup vs baseline: 1.3359x; 1.0069x over previous
//
#include <hip/hip_runtime.h>

#define OBS 128
#define HID 64
#define ACT 32
#define TT  128
#define BB  4096

typedef __attribute__((ext_vector_type(8))) short bf16x8;  // 8 bf16 (4 VGPRs)
typedef __attribute__((ext_vector_type(4))) float f32x4;

// tanh(v) = 1 - 2/(exp(2v)+1); exact at +-inf, ~1e-6 rel error (v_exp + v_rcp)
__device__ __forceinline__ float fast_tanh(float v) {
  const float e = __expf(2.0f * v);
  return 1.0f - 2.0f * __builtin_amdgcn_rcpf(e + 1.0f);
}

// f32 -> bf16 bits, round-to-nearest-even (prep + capture paths)
__device__ __forceinline__ short f2bf(float f) {
  const unsigned u = __float_as_uint(f);
  return (short)((u + 0x7FFFu + ((u >> 16) & 1u)) >> 16);
}

// HW packed f32x2 -> bf16x2 (RNE), gfx950; no builtin -> inline asm (T12/m240).
__device__ __forceinline__ unsigned cvtpk(float lo, float hi) {
  unsigned r;
  asm("v_cvt_pk_bf16_f32 %0, %1, %2" : "=v"(r) : "v"(lo), "v"(hi));
  return r;
}

// pack two f32x4 (C/D-layout quads) into one bf16x8 B-fragment (4 instrs)
__device__ __forceinline__ bf16x8 cvt8(const f32x4 s0, const f32x4 s1) {
  union { bf16x8 f; unsigned u[4]; } z;
  z.u[0] = cvtpk(s0[0], s0[1]); z.u[1] = cvtpk(s0[2], s0[3]);
  z.u[2] = cvtpk(s1[0], s1[1]); z.u[3] = cvtpk(s1[2], s1[3]);
  return z.f;
}

// pack [float4, float4] -> bf16x8
__device__ __forceinline__ bf16x8 cvt8f(const float4 lo, const float4 hi) {
  union { bf16x8 f; unsigned u[4]; } z;
  z.u[0] = cvtpk(lo.x, lo.y); z.u[1] = cvtpk(lo.z, lo.w);
  z.u[2] = cvtpk(hi.x, hi.y); z.u[3] = cvtpk(hi.z, hi.w);
  return z.f;
}

// LDS barrier: drain own ds ops, sync waves (NOT __syncthreads — no vmcnt drain)
__device__ __forceinline__ void lds_barrier() {
  asm volatile("s_waitcnt lgkmcnt(0)" ::: "memory");
  __builtin_amdgcn_s_barrier();
  asm volatile("" ::: "memory");
}

// ---------------------------------------------------------------------------
// Prep: fragment-ordered bf16 weight table in d_ws (capture uses frags 0..23;
// recur consumer gathers Wp1/Wp2 directly).
// ---------------------------------------------------------------------------
__global__ void prep_weights(const float* __restrict__ Wc1,
                             const float* __restrict__ Wc2,
                             const float* __restrict__ Wp1,
                             const float* __restrict__ Wp2,
                             short* __restrict__ ws)
{
  const int idx = blockIdx.x * blockDim.x + threadIdx.x;  // 0..(44*64-1)
  if (idx >= 44 * 64) return;
  const int f = idx >> 6, lane = idx & 63;
  const int r = lane & 15, G = lane >> 4;
  short o[8];
  if (f < 16) {
    const int m = f >> 2, kk = f & 3;  // std: k = 32kk + 8G + j
#pragma unroll
    for (int j = 0; j < 8; ++j)
      o[j] = f2bf(Wc1[(kk * 32 + 8 * G + j) * HID + 16 * m + r]);
  } else if (f < 40) {
    const int q = (f < 24) ? (f - 16) : (f < 32) ? (f - 24) : (f - 32);
    const float* W = (f < 24) ? Wc2 : (f < 32) ? Wp1 : Wp2;
    const int m = q >> 1, kk = q & 1;  // custom k-map (matches lane-resident C/D)
#pragma unroll
    for (int j = 0; j < 8; ++j) {
      const int k = (j < 4) ? (32 * kk + 4 * G + j)
                            : (32 * kk + 16 + 4 * G + (j - 4));
      o[j] = f2bf(W[k * HID + 16 * m + r]);
    }
  } else {
    const int m = f - 40;  // a-part, std map: k = HID + 8G + j
#pragma unroll
    for (int j = 0; j < 8; ++j)
      o[j] = f2bf(Wp1[(HID + 8 * G + j) * HID + 16 * m + r]);
  }
  bf16x8 v;
#pragma unroll
  for (int j = 0; j < 8; ++j) v[j] = o[j];
  *(bf16x8*)(ws + (size_t)idx * 8) = v;
}

// ---------------------------------------------------------------------------
// Phase 1: capture — BYTE-IDENTICAL to rounds 9..24 (deterministic LDS-weight
// form, HBM-bound ~65-75 us at 2 blocks/CU).
// ---------------------------------------------------------------------------
__global__ __launch_bounds__(256, 2) void capture_lds(
    const float* __restrict__ x,
    const short* __restrict__ wsw,
    const float* __restrict__ bc1, const float* __restrict__ bc2,
    float* __restrict__ capt)
{
  __shared__ bf16x8 wl[24 * 64];  // 24.5 KB fragment table

  const int tid  = threadIdx.x;
  const int lane = tid & 63;
  const int r    = lane & 15;   // tile-row (N dim)
  const int G    = lane >> 4;   // k-group
  const int wave = blockIdx.x * 4 + (tid >> 6);
  const int nwaves = gridDim.x * 4;

  for (int s = tid; s < 24 * 64; s += 256)
    wl[s] = ((const bf16x8*)wsw)[s];
  __syncthreads();

  f32x4 bias1[4], bias2[4];
#pragma unroll
  for (int m = 0; m < 4; ++m) {
    bias1[m] = *(const f32x4*)(bc1 + 16 * m + 4 * G);
    bias2[m] = *(const f32x4*)(bc2 + 16 * m + 4 * G);
  }

  for (int tile = wave; tile < (TT * BB) / 16; tile += nwaves) {
    asm volatile("" ::: "memory");

    const float* xrow = x + ((size_t)tile * 16 + r) * OBS;
    bf16x8 xa[4];
#pragma unroll
    for (int kk = 0; kk < 4; ++kk) {
      const float4 lo = *(const float4*)(xrow + kk * 32 + 8 * G);
      const float4 hi = *(const float4*)(xrow + kk * 32 + 8 * G + 4);
      bf16x8 f;
      f[0] = f2bf(lo.x); f[1] = f2bf(lo.y); f[2] = f2bf(lo.z); f[3] = f2bf(lo.w);
      f[4] = f2bf(hi.x); f[5] = f2bf(hi.y); f[6] = f2bf(hi.z); f[7] = f2bf(hi.w);
      xa[kk] = f;
    }

    float um[4][4];
#pragma unroll
    for (int m = 0; m < 4; ++m) {
      f32x4 acc = bias1[m];
#pragma unroll
      for (int kk = 0; kk < 4; ++kk)
        acc = __builtin_amdgcn_mfma_f32_16x16x32_bf16(wl[(m * 4 + kk) * 64 + lane],
                                                      xa[kk], acc, 0, 0, 0);
#pragma unroll
      for (int q = 0; q < 4; ++q) um[m][q] = fast_tanh(acc[q]);
    }

    bf16x8 b2[2];
#pragma unroll
    for (int kk = 0; kk < 2; ++kk) {
      bf16x8 f;
#pragma unroll
      for (int j = 0; j < 4; ++j) f[j]     = f2bf(um[2 * kk][j]);
#pragma unroll
      for (int j = 0; j < 4; ++j) f[4 + j] = f2bf(um[2 * kk + 1][j]);
      b2[kk] = f;
    }

    float* crow = capt + ((size_t)tile * 16 + r) * HID;
#pragma unroll
    for (int m = 0; m < 4; ++m) {
      f32x4 acc = bias2[m];
#pragma unroll
      for (int kk = 0; kk < 2; ++kk)
        acc = __builtin_amdgcn_mfma_f32_16x16x32_bf16(wl[(16 + m * 2 + kk) * 64 + lane],
                                                      b2[kk], acc, 0, 0, 0);
      float4 o;
      o.x = fast_tanh(acc[0]); o.y = fast_tanh(acc[1]);
      o.z = fast_tanh(acc[2]); o.w = fast_tanh(acc[3]);
      *(float4*)(crow + 16 * m + 4 * G) = o;
    }
  }
}

// ---------------------------------------------------------------------------
// Phase 2: recurrence — r24 structure with 4 STEPS PER BARRIER PHASE on an
// 8-slot ring, and the producer BATCHING all 4 stages' loads before one
// vmcnt wait (load-all/write-all source order). r24's producer exposed two
// serial ~600 cyc L3 round-trips per phase; now one per 4 steps -> producer
// phase ~900 cyc vs consumer ~6000, structurally hidden. Barriers 130 -> 66.
// Consumer body r24-verbatim (pinned weights, exp tanh). Slot parity: phase
// k consumer reads slots (4k..4k+3)&7, producer writes (4k+4..4k+7)&7 —
// disjoint. Grid: 256 blocks x 128 threads (1 block/CU; 2 waves).
// ---------------------------------------------------------------------------
__global__ __launch_bounds__(128, 1) void recur_pc(
    const float* __restrict__ h0,
    const float* __restrict__ g,
    const float* __restrict__ a,
    const float* __restrict__ Wp1, const float* __restrict__ bp1,
    const float* __restrict__ Wp2, const float* __restrict__ bp2,
    const float* __restrict__ z1buf,
    float* __restrict__ outs, float* __restrict__ hlast)
{
  __shared__ float zS[8][16][68];  // z slot: 16 rows x 64 (+4 pad)
  __shared__ float aS[8][16][36];  // a slot: 16 rows x 32 (+4 pad)
  __shared__ float gS[8][16];

  const int tid  = threadIdx.x;
  const int lane = tid & 63;
  const int wid  = __builtin_amdgcn_readfirstlane(tid >> 6);
  const int row0 = blockIdx.x * 16;

  if (wid == 1) {
    // ================= PRODUCER =================
    // batch-load 4 steps (q = 0..3 buffer index), then batch-write: loads all
    // issue before the first LDS write's vmcnt wait -> one L3 latency / phase
    float4 zb[4][4], ab[4][2];
    float gb[4];

#define P_LOAD4(t, q)                                                       \
    do {                                                                    \
      const size_t rb = (size_t)(t) * BB + row0;                            \
      const float* zp = z1buf + rb * HID;                                   \
      _Pragma("unroll")                                                     \
      for (int i = 0; i < 4; ++i)                                           \
        zb[q][i] = *(const float4*)(zp + i * 256 + lane * 4);               \
      const float* ap = a + rb * ACT;                                       \
      _Pragma("unroll")                                                     \
      for (int i = 0; i < 2; ++i)                                           \
        ab[q][i] = *(const float4*)(ap + i * 256 + lane * 4);               \
      gb[q] = (lane < 16) ? g[rb + lane] : 0.0f;                            \
    } while (0)

#define P_WRITE4(p, q)                                                      \
    do {                                                                    \
      _Pragma("unroll")                                                     \
      for (int i = 0; i < 4; ++i) {                                         \
        const int rr = i * 4 + (lane >> 4), cc = (lane & 15) * 4;           \
        *(float4*)&zS[p][rr][cc] = zb[q][i];                                \
      }                                                                     \
      _Pragma("unroll")                                                     \
      for (int i = 0; i < 2; ++i) {                                         \
        const int rr = i * 8 + (lane >> 3), cc = (lane & 7) * 4;            \
        *(float4*)&aS[p][rr][cc] = ab[q][i];                                \
      }                                                                     \
      if (lane < 16) gS[p][lane] = gb[q];                                   \
    } while (0)

    // prologue: steps 0..3 into slots 0..3
#pragma unroll
    for (int q = 0; q < 4; ++q) P_LOAD4(q, q);
#pragma unroll
    for (int q = 0; q < 4; ++q) P_WRITE4(q, q);
    lds_barrier();

    for (int k = 0; k < TT / 4; ++k) {
      const int tb = 4 * k + 4;
#pragma unroll
      for (int q = 0; q < 4; ++q) {
        const int t = (tb + q < TT) ? (tb + q) : (TT - 1);  // clamp
        P_LOAD4(t, q);
      }
#pragma unroll
      for (int q = 0; q < 4; ++q) P_WRITE4((tb + q) & 7, q);
      lds_barrier();
    }
  } else {
    // ================= CONSUMER =================
    const int r = lane & 15;
    const int G = lane >> 4;
    const int row = row0 + r;

    // weights gathered once; in-loop pin keeps them resident (r15)
    bf16x8 w1h[4][2], w2t[4][2], w1a[4];
#pragma unroll
    for (int m = 0; m < 4; ++m) {
#pragma unroll
      for (int kk = 0; kk < 2; ++kk) {
        bf16x8 f1, f2;
#pragma unroll
        for (int j = 0; j < 8; ++j) {
          const int k = (j < 4) ? (32 * kk + 4 * G + j)
                                : (32 * kk + 16 + 4 * G + (j - 4));
          f1[j] = f2bf(Wp1[k * HID + 16 * m + r]);
          f2[j] = f2bf(Wp2[k * HID + 16 * m + r]);
        }
        w1h[m][kk] = f1;
        w2t[m][kk] = f2;
      }
      bf16x8 fa;  // a-part, std map: k = HID + 8G + j
#pragma unroll
      for (int j = 0; j < 8; ++j)
        fa[j] = f2bf(Wp1[(HID + 8 * G + j) * HID + 16 * m + r]);
      w1a[m] = fa;
    }
    f32x4 bias1[4], bias2[4];
#pragma unroll
    for (int m = 0; m < 4; ++m) {
      bias1[m] = *(const f32x4*)(bp1 + 16 * m + 4 * G);
      bias2[m] = *(const f32x4*)(bp2 + 16 * m + 4 * G);
    }

    f32x4 hm[4];
#pragma unroll
    for (int m = 0; m < 4; ++m)
      hm[m] = *(const f32x4*)(h0 + (size_t)row * HID + 16 * m + 4 * G);
    bf16x8 hb0 = cvt8(hm[0], hm[1]);
    bf16x8 hb1 = cvt8(hm[2], hm[3]);

    lds_barrier();  // matches producer's initial-fill barrier

#define C_STEP(t)                                                              \
    do {                                                                       \
      const int p = (t) & 7;                                                   \
      const f32x4 Z0 = *(const f32x4*)&zS[p][r][4 * G];                        \
      const f32x4 Z1 = *(const f32x4*)&zS[p][r][16 + 4 * G];                   \
      const f32x4 Z2 = *(const f32x4*)&zS[p][r][32 + 4 * G];                   \
      const f32x4 Z3 = *(const f32x4*)&zS[p][r][48 + 4 * G];                   \
      const float4 AL = *(const float4*)&aS[p][r][8 * G];                      \
      const float4 AH = *(const float4*)&aS[p][r][8 * G + 4];                  \
      const float GV = gS[p][r];                                               \
      const bf16x8 ab2 = cvt8f(AL, AH);                                        \
      f32x4 um[4];                                                             \
      _Pragma("unroll")                                                        \
      for (int m = 0; m < 4; ++m) {                                            \
        f32x4 acc = bias1[m];                                                  \
        acc = __builtin_amdgcn_mfma_f32_16x16x32_bf16(w1h[m][0], hb0, acc, 0, 0, 0); \
        acc = __builtin_amdgcn_mfma_f32_16x16x32_bf16(w1h[m][1], hb1, acc, 0, 0, 0); \
        acc = __builtin_amdgcn_mfma_f32_16x16x32_bf16(w1a[m], ab2, acc, 0, 0, 0); \
        f32x4 u;                                                               \
        u[0] = fast_tanh(acc[0]); u[1] = fast_tanh(acc[1]);                    \
        u[2] = fast_tanh(acc[2]); u[3] = fast_tanh(acc[3]);                    \
        um[m] = u;                                                             \
      }                                                                        \
      const bf16x8 ub0 = cvt8(um[0], um[1]);                                   \
      const bf16x8 ub1 = cvt8(um[2], um[3]);                                   \
      const size_t ob = ((size_t)(t) * BB + row) * HID;                        \
      _Pragma("unroll")                                                        \
      for (int m = 0; m < 4; ++m) {                                            \
        f32x4 acc = bias2[m];                                                  \
        acc = __builtin_amdgcn_mfma_f32_16x16x32_bf16(w2t[m][0], ub0, acc, 0, 0, 0); \
        acc = __builtin_amdgcn_mfma_f32_16x16x32_bf16(w2t[m][1], ub1, acc, 0, 0, 0); \
        const f32x4 zz = (m == 0) ? Z0 : (m == 1) ? Z1 : (m == 2) ? Z2 : Z3;   \
        f32x4 hn;                                                              \
        hn[0] = fmaf(GV, fast_tanh(acc[0]) - zz[0], zz[0]);                    \
        hn[1] = fmaf(GV, fast_tanh(acc[1]) - zz[1], zz[1]);                    \
        hn[2] = fmaf(GV, fast_tanh(acc[2]) - zz[2], zz[2]);                    \
        hn[3] = fmaf(GV, fast_tanh(acc[3]) - zz[3], zz[3]);                    \
        hm[m] = hn;                                                            \
        *(f32x4*)(outs + ob + 16 * m + 4 * G) = hn;                            \
      }                                                                        \
      hb0 = cvt8(hm[0], hm[1]);                                                \
      hb1 = cvt8(hm[2], hm[3]);                                                \
    } while (0)

    for (int k = 0; k < TT / 4; ++k) {
      // in-loop pin: weights/biases are loop-carried opaque values
#pragma unroll
      for (int m = 0; m < 4; ++m) {
        asm volatile("" : "+v"(w1h[m][0]), "+v"(w1h[m][1]));
        asm volatile("" : "+v"(w2t[m][0]), "+v"(w2t[m][1]));
        asm volatile("" : "+v"(w1a[m]));
        asm volatile("" : "+v"(bias1[m]), "+v"(bias2[m]));
      }

      C_STEP(4 * k);
      C_STEP(4 * k + 1);
      C_STEP(4 * k + 2);
      C_STEP(4 * k + 3);
      lds_barrier();
    }

#pragma unroll
    for (int m = 0; m < 4; ++m)
      *(f32x4*)(hlast + (size_t)row * HID + 16 * m + 4 * G) = hm[m];
  }
}

extern "C" void kernel_launch(void* const* d_in, const int* in_sizes, int n_in,
                              void* d_out, int out_size, void* d_ws, size_t ws_size,
                              hipStream_t stream) {
  const float* x   = (const float*)d_in[0];
  const float* h0  = (const float*)d_in[1];
  const float* g   = (const float*)d_in[2];
  const float* a   = (const float*)d_in[3];
  const float* Wc1 = (const float*)d_in[4];
  const float* bc1 = (const float*)d_in[5];
  const float* Wc2 = (const float*)d_in[6];
  const float* bc2 = (const float*)d_in[7];
  const float* Wp1 = (const float*)d_in[8];
  const float* bp1 = (const float*)d_in[9];
  const float* Wp2 = (const float*)d_in[10];
  const float* bp2 = (const float*)d_in[11];

  float* out   = (float*)d_out;
  float* outs  = out;                                   // [T,B,H]
  float* hlast = out + (size_t)TT * BB * HID;           // [1,B,H]
  float* capt  = hlast + (size_t)BB * HID;              // [T,B,H]
  short* wsw   = (short*)d_ws;                          // 44 KB fragment buffer

  prep_weights<<<dim3(11), dim3(256), 0, stream>>>(Wc1, Wc2, Wp1, Wp2, wsw);
  capture_lds<<<dim3(2048), dim3(256), 0, stream>>>(x, wsw, bc1, bc2, capt);
  recur_pc<<<dim3(BB / 16), dim3(128), 0, stream>>>(h0, g, a, Wp1, bp1, Wp2, bp2,
                                                    capt, outs, hlast);
}